// Round 8
// baseline (1553.480 us; speedup 1.0000x reference)
//
#include <hip/hip_runtime.h>

#define NN 50000
#define NE 800000
#define HD 128
#define INN 11
#define NL 4
#define NG16 3125        // 16-row node groups
#define BTS 132          // LDS K stride (shorts)
#define K1S 292          // nk1 K stride
#define NB  196          // CSR scan blocks (196*256 >= NN)

typedef __attribute__((ext_vector_type(8))) short bf16x8;
typedef __attribute__((ext_vector_type(4))) float f32x4;
typedef __attribute__((ext_vector_type(2))) float f32x2;

__device__ __forceinline__ float silu_f(float x) {
    return x * __builtin_amdgcn_rcpf(1.0f + __expf(-x));
}

__device__ __forceinline__ short f2bf(float x) {
    unsigned u = __float_as_uint(x);
    return (short)((u + 0x7FFFu + ((u >> 16) & 1u)) >> 16);
}
__device__ __forceinline__ unsigned f2bf2u(float lo, float hi) {
    unsigned a = __float_as_uint(lo), b = __float_as_uint(hi);
    a = (a + 0x7FFFu + ((a >> 16) & 1u)) >> 16;
    b = (b + 0x7FFFu + ((b >> 16) & 1u)) & 0xFFFF0000u;
    return a | b;
}
__device__ __forceinline__ bf16x8 pack8(float4 a, float4 b) {
    bf16x8 r;
    r[0] = f2bf(a.x); r[1] = f2bf(a.y); r[2] = f2bf(a.z); r[3] = f2bf(a.w);
    r[4] = f2bf(b.x); r[5] = f2bf(b.y); r[6] = f2bf(b.z); r[7] = f2bf(b.w);
    return r;
}

// ---------------- embedding (writes f32 h and bf16 shadow hb) ----------------
__global__ __launch_bounds__(256) void embed_kernel(
    const float* __restrict__ h0, const float* __restrict__ w,
    const float* __restrict__ b, float* __restrict__ h, short* __restrict__ hb)
{
    int idx = blockIdx.x * 256 + threadIdx.x;
    if (idx >= NN * HD) return;
    int n = idx >> 7, j = idx & 127;
    float acc = b[j];
    #pragma unroll
    for (int k = 0; k < INN; ++k)
        acc += h0[n * INN + k] * w[k * HD + j];
    h[idx] = acc;
    hb[idx] = f2bf(acc);
}

// ---------------- h0 bf16 pack (once): layout matches afr[8] fragment ----------------
__global__ __launch_bounds__(256) void h0_pack(
    const float* __restrict__ h0, short* __restrict__ h0b)
{
    int idx = blockIdx.x * 256 + threadIdx.x;
    if (idx >= NN * 32) return;
    int n = idx >> 5, j = idx & 31;
    h0b[idx] = (j < INN) ? f2bf(h0[n * INN + j]) : (short)0;
}

// ---------------- CSR build ----------------
__global__ __launch_bounds__(256) void csr_zero(int* __restrict__ cnt)
{
    int i = blockIdx.x * 256 + threadIdx.x;
    if (i < NN) cnt[i] = 0;
}

__global__ __launch_bounds__(256) void csr_hist(const int* __restrict__ ei, int* __restrict__ cnt)
{
    int e = blockIdx.x * 256 + threadIdx.x;
    atomicAdd(&cnt[ei[e]], 1);
}

__global__ __launch_bounds__(256) void csr_blocksum(
    const int* __restrict__ cnt, int* __restrict__ bsum)
{
    __shared__ int red[4];
    int j = blockIdx.x * 256 + threadIdx.x;
    int v = (j < NN) ? cnt[j] : 0;
    #pragma unroll
    for (int off = 1; off < 64; off <<= 1) v += __shfl_xor(v, off, 64);
    int lane = threadIdx.x & 63, wv = threadIdx.x >> 6;
    if (lane == 0) red[wv] = v;
    __syncthreads();
    if (threadIdx.x == 0)
        bsum[blockIdx.x] = red[0] + red[1] + red[2] + red[3];
}

__global__ __launch_bounds__(256) void csr_scanpart(
    const int* __restrict__ bsum, int* __restrict__ boff, int* __restrict__ rowptr)
{
    __shared__ int part[256];
    int t = threadIdx.x;
    int v = (t < NB) ? bsum[t] : 0;
    part[t] = v;
    __syncthreads();
    #pragma unroll
    for (int off = 1; off < 256; off <<= 1) {
        int tmp = (t >= off) ? part[t - off] : 0;
        __syncthreads();
        part[t] += tmp;
        __syncthreads();
    }
    if (t < NB) boff[t] = part[t] - v;          // exclusive
    if (t == NB - 1) rowptr[NN] = part[t];      // total
}

__global__ __launch_bounds__(256) void csr_emit(
    const int* __restrict__ cnt, const int* __restrict__ boff,
    int* __restrict__ rowptr, int* __restrict__ cursor)
{
    __shared__ int part[256];
    int t = threadIdx.x;
    int j = blockIdx.x * 256 + t;
    int v = (j < NN) ? cnt[j] : 0;
    part[t] = v;
    __syncthreads();
    #pragma unroll
    for (int off = 1; off < 256; off <<= 1) {
        int tmp = (t >= off) ? part[t - off] : 0;
        __syncthreads();
        part[t] += tmp;
        __syncthreads();
    }
    if (j < NN) {
        int r = boff[blockIdx.x] + part[t] - v;
        rowptr[j] = r;
        cursor[j] = r;
    }
}

__global__ __launch_bounds__(256) void csr_fill(
    const int* __restrict__ ei, int* __restrict__ cursor, int* __restrict__ eidx)
{
    int e = blockIdx.x * 256 + threadIdx.x;
    int r = ei[e];
    int p = atomicAdd(&cursor[r], 1);
    eidx[p] = e;
}

// ---------------- per-edge data, CSR order; ed = {r*64, c*64, rad, mask} ----------------
__global__ __launch_bounds__(256) void edge_pre(
    const int* __restrict__ ei, const int* __restrict__ eidx,
    const float* __restrict__ x, const float* __restrict__ emask,
    int4* __restrict__ ed_p)
{
    int p = blockIdx.x * 256 + threadIdx.x;
    int e = eidx[p];
    int r = ei[e], c = ei[NE + e];
    float dx = x[3 * r]     - x[3 * c];
    float dy = x[3 * r + 1] - x[3 * c + 1];
    float dz = x[3 * r + 2] - x[3 * c + 2];
    float rad = dx * dx + dy * dy + dz * dz;
    ed_p[p] = make_int4(r * 64, c * 64, __float_as_int(rad), __float_as_int(emask[e]));
}

// zero the 16 slack rows of vbuf (once, before the layer loop)
__global__ __launch_bounds__(1024) void vpad_zero(unsigned* __restrict__ vb32)
{
    vb32[(size_t)NE * 64 + threadIdx.x] = 0u;
}

// ---------------- t|u = h @ ew1 halves — ONE pass from bf16 hb (vbuf-head alias) ----------------
// Safe alias: nk2(l) writes hb; tu(l+1) reads it; edge_v(l+1) clobbers vbuf afterwards.
// t half folds eb1: t' = t + b1. No f32 read, no packing, both BTs in 67.6 KB LDS.
__global__ __launch_bounds__(512) void tu_mfma(
    const short* __restrict__ hb, const float* __restrict__ ew1_l,
    const float* __restrict__ eb1_l,
    short* __restrict__ tb, short* __restrict__ ub)
{
    __shared__ __align__(16) short BTt[128 * BTS];
    __shared__ __align__(16) short BTu[128 * BTS];
    for (int i = threadIdx.x; i < 128 * 128; i += 512) {
        int c = i >> 7, k = i & 127;
        BTt[c * BTS + k] = f2bf(ew1_l[k * HD + c]);
        BTu[c * BTS + k] = f2bf(ew1_l[(128 + k) * HD + c]);
    }
    int wv = threadIdx.x >> 6, lane = threadIdx.x & 63;
    int ln15 = lane & 15, quad = lane >> 4;
    __syncthreads();

    for (int g = blockIdx.x * 8 + wv; g < NG16; g += gridDim.x * 8) {
        int row = g * 16 + ln15;
        const short* hrow = hb + (size_t)row * HD + quad * 8;
        bf16x8 afr[4];
        #pragma unroll
        for (int kt = 0; kt < 4; ++kt)
            afr[kt] = *(const bf16x8*)(hrow + kt * 32);

        #pragma unroll
        for (int ct = 0; ct < 8; ++ct) {
            f32x4 acc = {0.f, 0.f, 0.f, 0.f};
            #pragma unroll
            for (int kt = 0; kt < 4; ++kt) {
                bf16x8 bfr = *(const bf16x8*)&BTt[(ct * 16 + ln15) * BTS + kt * 32 + quad * 8];
                acc = __builtin_amdgcn_mfma_f32_16x16x32_bf16(afr[kt], bfr, acc, 0, 0, 0);
            }
            int col = ct * 16 + ln15;
            float bb = eb1_l[col];
            #pragma unroll
            for (int r4 = 0; r4 < 4; ++r4) {
                int orow = g * 16 + quad * 4 + r4;
                tb[orow * HD + col] = f2bf(acc[r4] + bb);
            }
        }
        #pragma unroll
        for (int ct = 0; ct < 8; ++ct) {
            f32x4 acc = {0.f, 0.f, 0.f, 0.f};
            #pragma unroll
            for (int kt = 0; kt < 4; ++kt) {
                bf16x8 bfr = *(const bf16x8*)&BTu[(ct * 16 + ln15) * BTS + kt * 32 + quad * 8];
                acc = __builtin_amdgcn_mfma_f32_16x16x32_bf16(afr[kt], bfr, acc, 0, 0, 0);
            }
            int col = ct * 16 + ln15;
            #pragma unroll
            for (int r4 = 0; r4 < 4; ++r4) {
                int orow = g * 16 + quad * 4 + r4;
                ub[orow * HD + col] = f2bf(acc[r4]);
            }
        }
    }
}

// ---------------- edge v-compute: streaming, no LDS, no MFMA ----------------
__global__ __launch_bounds__(512) void edge_v_kernel(
    const short* __restrict__ tb, const short* __restrict__ ub,
    const int4* __restrict__ ed_p, const int* __restrict__ eidx,
    const float* __restrict__ eattr,
    const float* __restrict__ ew1_l,
    short* __restrict__ vbuf)
{
    int cp = threadIdx.x & 63;
    int c0 = cp * 2;
    f32x2 wr2  = *(const f32x2*)&ew1_l[256 * HD + c0];
    f32x2 wa02 = *(const f32x2*)&ew1_l[257 * HD + c0];
    f32x2 wa12 = *(const f32x2*)&ew1_l[258 * HD + c0];
    f32x2 wa22 = *(const f32x2*)&ew1_l[259 * HD + c0];
    f32x2 wa32 = *(const f32x2*)&ew1_l[260 * HD + c0];

    const unsigned* tb32 = (const unsigned*)tb;
    const unsigned* ub32 = (const unsigned*)ub;
    const float4*   ea4  = (const float4*)eattr;
    unsigned*       vb32 = (unsigned*)vbuf;

    int w  = (blockIdx.x * 512 + threadIdx.x) >> 6;
    int nw = gridDim.x * 8;

    for (int p0 = w * 4; p0 < NE; p0 += nw * 4) {      // NE % 4 == 0
        int4 edv[4]; unsigned twv[4], uwv[4]; float4 eav[4];
        #pragma unroll
        for (int j = 0; j < 4; ++j) edv[j] = ed_p[p0 + j];
        #pragma unroll
        for (int j = 0; j < 4; ++j) {
            twv[j] = tb32[edv[j].x + cp];
            uwv[j] = ub32[edv[j].y + cp];
            eav[j] = ea4[eidx[p0 + j]];
        }
        #pragma unroll
        for (int j = 0; j < 4; ++j) {
            float rad = __int_as_float(edv[j].z);
            f32x2 s;
            s.x = __uint_as_float(twv[j] << 16)        + __uint_as_float(uwv[j] << 16);
            s.y = __uint_as_float(twv[j] & 0xFFFF0000u) + __uint_as_float(uwv[j] & 0xFFFF0000u);
            s += rad * wr2;
            s += eav[j].x * wa02;
            s += eav[j].y * wa12;
            s += eav[j].z * wa22;
            s += eav[j].w * wa32;
            vb32[(size_t)(p0 + j) * 64 + cp] = f2bf2u(silu_f(s.x), silu_f(s.y));
        }
    }
}

// ---------------- edge MFMA + aggregation: wave per node (round-3 body, proven 125 us) ----------------
// b2 hoisted to 8 registers (was per-tile LDS reads). Unclamped bounds (clamps spill, r4/r5).
__global__ __launch_bounds__(512) void edge_agg_kernel(
    const short* __restrict__ vbuf, const int4* __restrict__ ed_p,
    const int* __restrict__ rowptr,
    const float* __restrict__ ew2_l, const float* __restrict__ eb2_l,
    short* __restrict__ aggb)
{
    __shared__ __align__(16) short BT[128 * BTS];

    for (int i = threadIdx.x; i < 128 * 128; i += 512) {
        int k = i >> 7, n = i & 127;
        BT[n * BTS + k] = f2bf(ew2_l[i]);
    }

    int lane = threadIdx.x & 63;
    int wv   = threadIdx.x >> 6;
    int ln15 = lane & 15;
    int quad = lane >> 4;

    float b2r[8];
    #pragma unroll
    for (int ct = 0; ct < 8; ++ct) b2r[ct] = eb2_l[ct * 16 + ln15];
    __syncthreads();

    for (int n = blockIdx.x * 8 + wv; n < NN; n += gridDim.x * 8) {
        int s = rowptr[n], en = rowptr[n + 1];

        float sums[8];
        #pragma unroll
        for (int ct = 0; ct < 8; ++ct) sums[ct] = 0.f;

        for (int base = s; base < en; base += 16) {
            const short* vrow = vbuf + (size_t)(base + ln15) * HD + quad * 8;
            bf16x8 afr[4];
            #pragma unroll
            for (int kt = 0; kt < 4; ++kt)
                afr[kt] = *(const bf16x8*)(vrow + kt * 32);

            int pr = base + quad * 4;
            float mk0 = (pr + 0 < en) ? __int_as_float(ed_p[pr + 0].w) : 0.f;
            float mk1 = (pr + 1 < en) ? __int_as_float(ed_p[pr + 1].w) : 0.f;
            float mk2 = (pr + 2 < en) ? __int_as_float(ed_p[pr + 2].w) : 0.f;
            float mk3 = (pr + 3 < en) ? __int_as_float(ed_p[pr + 3].w) : 0.f;

            #pragma unroll
            for (int ct = 0; ct < 8; ++ct) {
                f32x4 acc = {0.f, 0.f, 0.f, 0.f};
                #pragma unroll
                for (int kt = 0; kt < 4; ++kt) {
                    bf16x8 bfr = *(const bf16x8*)&BT[(ct * 16 + ln15) * BTS + kt * 32 + quad * 8];
                    acc = __builtin_amdgcn_mfma_f32_16x16x32_bf16(afr[kt], bfr, acc, 0, 0, 0);
                }
                float b2c = b2r[ct];
                sums[ct] += silu_f(acc[0] + b2c) * mk0 + silu_f(acc[1] + b2c) * mk1
                          + silu_f(acc[2] + b2c) * mk2 + silu_f(acc[3] + b2c) * mk3;
            }
        }

        #pragma unroll
        for (int ct = 0; ct < 8; ++ct) {
            float v = sums[ct];
            v += __shfl_xor(v, 16, 64);
            v += __shfl_xor(v, 32, 64);
            sums[ct] = v;
        }
        float vA = (quad & 2) ? ((quad & 1) ? sums[6] : sums[4])
                              : ((quad & 1) ? sums[2] : sums[0]);
        float vB = (quad & 2) ? ((quad & 1) ? sums[7] : sums[5])
                              : ((quad & 1) ? sums[3] : sums[1]);
        int colA = quad * 32 + ln15;
        aggb[(size_t)n * HD + colA]      = f2bf(vA);
        aggb[(size_t)n * HD + colA + 16] = f2bf(vB);
    }
}

// ---------------- node MLP layer 1 (f32 h + pack; agg bf16; h0 via precomputed h0b) ----------------
__global__ __launch_bounds__(512) void nk1_mfma(
    const float* __restrict__ h, const short* __restrict__ aggb,
    const short* __restrict__ h0b,
    const float* __restrict__ nw1_l, const float* __restrict__ nb1_l,
    short* __restrict__ qb)
{
    __shared__ __align__(16) short BT[64 * K1S];
    int c0 = blockIdx.y * 64;
    for (int i = threadIdx.x; i < 64 * 288; i += 512) {
        int c = i / 288, k = i - c * 288;
        BT[c * K1S + k] = (k < 267) ? f2bf(nw1_l[k * HD + c0 + c]) : (short)0;
    }
    int wv = threadIdx.x >> 6, lane = threadIdx.x & 63;
    int ln15 = lane & 15, quad = lane >> 4;
    __syncthreads();

    for (int g = blockIdx.x * 8 + wv; g < NG16; g += gridDim.x * 8) {
        int row = g * 16 + ln15;
        const float* hrow = h + row * HD;
        const short* arow = aggb + (size_t)row * HD + quad * 8;
        bf16x8 afr[9];
        #pragma unroll
        for (int kt = 0; kt < 4; ++kt) {
            float4 x0 = *(const float4*)(hrow + kt * 32 + quad * 8);
            float4 x1 = *(const float4*)(hrow + kt * 32 + quad * 8 + 4);
            afr[kt] = pack8(x0, x1);
        }
        #pragma unroll
        for (int kt = 0; kt < 4; ++kt)
            afr[4 + kt] = *(const bf16x8*)(arow + kt * 32);
        afr[8] = *(const bf16x8*)(h0b + (size_t)row * 32 + quad * 8);

        #pragma unroll
        for (int ct = 0; ct < 4; ++ct) {
            f32x4 acc = {0.f, 0.f, 0.f, 0.f};
            #pragma unroll
            for (int kt = 0; kt < 9; ++kt) {
                bf16x8 bfr = *(const bf16x8*)&BT[(ct * 16 + ln15) * K1S + kt * 32 + quad * 8];
                acc = __builtin_amdgcn_mfma_f32_16x16x32_bf16(afr[kt], bfr, acc, 0, 0, 0);
            }
            int col = c0 + ct * 16 + ln15;
            float b = nb1_l[col];
            #pragma unroll
            for (int r4 = 0; r4 < 4; ++r4) {
                int orow = g * 16 + quad * 4 + r4;
                qb[orow * HD + col] = f2bf(silu_f(acc[r4] + b));
            }
        }
    }
}

// ---------------- node MLP layer 2 + residual (writes f32 h and bf16 hb shadow) ----------------
__global__ __launch_bounds__(512) void nk2_mfma(
    const short* __restrict__ qb, const float* __restrict__ nw2_l,
    const float* __restrict__ nb2_l, float* __restrict__ h, short* __restrict__ hb)
{
    __shared__ __align__(16) short BT[128 * BTS];
    for (int i = threadIdx.x; i < 128 * 128; i += 512) {
        int c = i >> 7, k = i & 127;
        BT[c * BTS + k] = f2bf(nw2_l[k * HD + c]);
    }
    int wv = threadIdx.x >> 6, lane = threadIdx.x & 63;
    int ln15 = lane & 15, quad = lane >> 4;
    __syncthreads();

    for (int g = blockIdx.x * 8 + wv; g < NG16; g += gridDim.x * 8) {
        int row = g * 16 + ln15;
        bf16x8 afr[4];
        #pragma unroll
        for (int kt = 0; kt < 4; ++kt)
            afr[kt] = *(const bf16x8*)(qb + row * HD + kt * 32 + quad * 8);

        #pragma unroll
        for (int ct = 0; ct < 8; ++ct) {
            f32x4 acc = {0.f, 0.f, 0.f, 0.f};
            #pragma unroll
            for (int kt = 0; kt < 4; ++kt) {
                bf16x8 bfr = *(const bf16x8*)&BT[(ct * 16 + ln15) * BTS + kt * 32 + quad * 8];
                acc = __builtin_amdgcn_mfma_f32_16x16x32_bf16(afr[kt], bfr, acc, 0, 0, 0);
            }
            int col = ct * 16 + ln15;
            float b = nb2_l[col];
            #pragma unroll
            for (int r4 = 0; r4 < 4; ++r4) {
                int orow = g * 16 + quad * 4 + r4;
                float hv = h[orow * HD + col] + acc[r4] + b;
                h[orow * HD + col]  = hv;
                hb[orow * HD + col] = f2bf(hv);
            }
        }
    }
}

extern "C" void kernel_launch(void* const* d_in, const int* in_sizes, int n_in,
                              void* d_out, int out_size, void* d_ws, size_t ws_size,
                              hipStream_t stream)
{
    const float* h0    = (const float*)d_in[0];
    const float* x     = (const float*)d_in[1];
    const int*   ei    = (const int*)d_in[2];
    const float* eattr = (const float*)d_in[3];
    const float* emask = (const float*)d_in[5];
    const float* emb_w = (const float*)d_in[7];
    const float* emb_b = (const float*)d_in[8];
    const float* ew1   = (const float*)d_in[9];
    const float* eb1   = (const float*)d_in[10];
    const float* ew2   = (const float*)d_in[11];
    const float* eb2   = (const float*)d_in[12];
    const float* nw1   = (const float*)d_in[13];
    const float* nb1   = (const float*)d_in[14];
    const float* nw2   = (const float*)d_in[15];
    const float* nb2   = (const float*)d_in[16];

    float* h = (float*)d_out;

    // workspace layout (~262.9 MB of 268.4 MB)
    short*  tb     = (short*)d_ws;                          // NN*HD bf16
    short*  ub     = tb + (size_t)NN * HD;                  // NN*HD bf16
    short*  aggb   = ub + (size_t)NN * HD;                  // NN*HD bf16
    short*  vbuf   = aggb + (size_t)NN * HD;                // (NE+16)*HD bf16
    int4*   ed_p   = (int4*)(vbuf + (size_t)(NE + 16) * HD);// NE int4
    int*    rowptr = (int*)(ed_p + NE);                     // NN+1
    int*    cnt    = rowptr + NN + 1;                       // NN
    int*    cursor = cnt + NN;                              // NN
    int*    eidx   = cursor + NN;                           // NE
    int*    bsum   = eidx + NE;                             // NB
    int*    boff   = bsum + NB;                             // NB
    short*  h0b    = (short*)(boff + NB);                   // NN*32 bf16 (3.2 MB)
    short*  qb     = tb;                                    // alias (tb dead by nk1)
    short*  hb     = vbuf;                                  // alias: written by embed/nk2(l),
                                                            // read ONLY by tu(l+1) BEFORE edge_v(l+1)
                                                            // rewrites vbuf. Safe by stream order.

    csr_zero<<<(NN + 255) / 256, 256, 0, stream>>>(cnt);
    csr_hist<<<NE / 256, 256, 0, stream>>>(ei, cnt);
    csr_blocksum<<<NB, 256, 0, stream>>>(cnt, bsum);
    csr_scanpart<<<1, 256, 0, stream>>>(bsum, boff, rowptr);
    csr_emit<<<NB, 256, 0, stream>>>(cnt, boff, rowptr, cursor);
    csr_fill<<<NE / 256, 256, 0, stream>>>(ei, cursor, eidx);
    edge_pre<<<NE / 256, 256, 0, stream>>>(ei, eidx, x, emask, ed_p);
    vpad_zero<<<1, 1024, 0, stream>>>((unsigned*)vbuf);
    h0_pack<<<(NN * 32 + 255) / 256, 256, 0, stream>>>(h0, h0b);

    embed_kernel<<<(NN * HD + 255) / 256, 256, 0, stream>>>(h0, emb_w, emb_b, h, hb);

    dim3 gn1(128, 2);
    for (int l = 0; l < NL; ++l) {
        tu_mfma<<<256, 512, 0, stream>>>(hb, ew1 + l * 261 * HD, eb1 + l * HD, tb, ub);
        edge_v_kernel<<<1024, 512, 0, stream>>>(tb, ub, ed_p, eidx, eattr,
            ew1 + l * 261 * HD, vbuf);
        edge_agg_kernel<<<1024, 512, 0, stream>>>(vbuf, ed_p, rowptr,
            ew2 + l * HD * HD, eb2 + l * HD, aggb);
        nk1_mfma<<<gn1, 512, 0, stream>>>(h, aggb, h0b,
            nw1 + l * 267 * HD, nb1 + l * HD, qb);
        nk2_mfma<<<128, 512, 0, stream>>>(qb, nw2 + l * HD * HD, nb2 + l * HD, h, hb);
    }
}

// Round 9
// 1540.650 us; speedup vs baseline: 1.0083x; 1.0083x over previous
//
#include <hip/hip_runtime.h>

#define NN 50000
#define NE 800000
#define HD 128
#define INN 11
#define NL 4
#define NG16 3125        // 16-row node groups
#define BTS 132          // LDS K stride (shorts)
#define K1S 292          // nk1 K stride
#define NB  196          // CSR scan blocks (196*256 >= NN)

typedef __attribute__((ext_vector_type(8))) short bf16x8;
typedef __attribute__((ext_vector_type(4))) float f32x4;
typedef __attribute__((ext_vector_type(2))) float f32x2;

__device__ __forceinline__ float silu_f(float x) {
    return x * __builtin_amdgcn_rcpf(1.0f + __expf(-x));
}

__device__ __forceinline__ short f2bf(float x) {
    unsigned u = __float_as_uint(x);
    return (short)((u + 0x7FFFu + ((u >> 16) & 1u)) >> 16);
}
__device__ __forceinline__ unsigned f2bf2u(float lo, float hi) {
    unsigned a = __float_as_uint(lo), b = __float_as_uint(hi);
    a = (a + 0x7FFFu + ((a >> 16) & 1u)) >> 16;
    b = (b + 0x7FFFu + ((b >> 16) & 1u)) & 0xFFFF0000u;
    return a | b;
}
__device__ __forceinline__ bf16x8 pack8(float4 a, float4 b) {
    bf16x8 r;
    r[0] = f2bf(a.x); r[1] = f2bf(a.y); r[2] = f2bf(a.z); r[3] = f2bf(a.w);
    r[4] = f2bf(b.x); r[5] = f2bf(b.y); r[6] = f2bf(b.z); r[7] = f2bf(b.w);
    return r;
}

// ---------------- embedding ----------------
__global__ __launch_bounds__(256) void embed_kernel(
    const float* __restrict__ h0, const float* __restrict__ w,
    const float* __restrict__ b, float* __restrict__ h)
{
    int idx = blockIdx.x * 256 + threadIdx.x;
    if (idx >= NN * HD) return;
    int n = idx >> 7, j = idx & 127;
    float acc = b[j];
    #pragma unroll
    for (int k = 0; k < INN; ++k)
        acc += h0[n * INN + k] * w[k * HD + j];
    h[idx] = acc;
}

// ---------------- h0 bf16 pack (once): layout matches afr[8] fragment ----------------
__global__ __launch_bounds__(256) void h0_pack(
    const float* __restrict__ h0, short* __restrict__ h0b)
{
    int idx = blockIdx.x * 256 + threadIdx.x;
    if (idx >= NN * 32) return;
    int n = idx >> 5, j = idx & 31;
    h0b[idx] = (j < INN) ? f2bf(h0[n * INN + j]) : (short)0;
}

// ---------------- CSR build ----------------
__global__ __launch_bounds__(256) void csr_zero(int* __restrict__ cnt)
{
    int i = blockIdx.x * 256 + threadIdx.x;
    if (i < NN) cnt[i] = 0;
}

__global__ __launch_bounds__(256) void csr_hist(const int* __restrict__ ei, int* __restrict__ cnt)
{
    int e = blockIdx.x * 256 + threadIdx.x;
    atomicAdd(&cnt[ei[e]], 1);
}

__global__ __launch_bounds__(256) void csr_blocksum(
    const int* __restrict__ cnt, int* __restrict__ bsum)
{
    __shared__ int red[4];
    int j = blockIdx.x * 256 + threadIdx.x;
    int v = (j < NN) ? cnt[j] : 0;
    #pragma unroll
    for (int off = 1; off < 64; off <<= 1) v += __shfl_xor(v, off, 64);
    int lane = threadIdx.x & 63, wv = threadIdx.x >> 6;
    if (lane == 0) red[wv] = v;
    __syncthreads();
    if (threadIdx.x == 0)
        bsum[blockIdx.x] = red[0] + red[1] + red[2] + red[3];
}

__global__ __launch_bounds__(256) void csr_scanpart(
    const int* __restrict__ bsum, int* __restrict__ boff, int* __restrict__ rowptr)
{
    __shared__ int part[256];
    int t = threadIdx.x;
    int v = (t < NB) ? bsum[t] : 0;
    part[t] = v;
    __syncthreads();
    #pragma unroll
    for (int off = 1; off < 256; off <<= 1) {
        int tmp = (t >= off) ? part[t - off] : 0;
        __syncthreads();
        part[t] += tmp;
        __syncthreads();
    }
    if (t < NB) boff[t] = part[t] - v;          // exclusive
    if (t == NB - 1) rowptr[NN] = part[t];      // total
}

__global__ __launch_bounds__(256) void csr_emit(
    const int* __restrict__ cnt, const int* __restrict__ boff,
    int* __restrict__ rowptr, int* __restrict__ cursor)
{
    __shared__ int part[256];
    int t = threadIdx.x;
    int j = blockIdx.x * 256 + t;
    int v = (j < NN) ? cnt[j] : 0;
    part[t] = v;
    __syncthreads();
    #pragma unroll
    for (int off = 1; off < 256; off <<= 1) {
        int tmp = (t >= off) ? part[t - off] : 0;
        __syncthreads();
        part[t] += tmp;
        __syncthreads();
    }
    if (j < NN) {
        int r = boff[blockIdx.x] + part[t] - v;
        rowptr[j] = r;
        cursor[j] = r;
    }
}

__global__ __launch_bounds__(256) void csr_fill(
    const int* __restrict__ ei, int* __restrict__ cursor, int* __restrict__ eidx)
{
    int e = blockIdx.x * 256 + threadIdx.x;
    int r = ei[e];
    int p = atomicAdd(&cursor[r], 1);
    eidx[p] = e;
}

// ---------------- per-edge data, CSR order; ed = {r*64, c*64, rad, mask} ----------------
__global__ __launch_bounds__(256) void edge_pre(
    const int* __restrict__ ei, const int* __restrict__ eidx,
    const float* __restrict__ x, const float* __restrict__ emask,
    int4* __restrict__ ed_p)
{
    int p = blockIdx.x * 256 + threadIdx.x;
    int e = eidx[p];
    int r = ei[e], c = ei[NE + e];
    float dx = x[3 * r]     - x[3 * c];
    float dy = x[3 * r + 1] - x[3 * c + 1];
    float dz = x[3 * r + 2] - x[3 * c + 2];
    float rad = dx * dx + dy * dy + dz * dz;
    ed_p[p] = make_int4(r * 64, c * 64, __float_as_int(rad), __float_as_int(emask[e]));
}

// zero the 16 slack rows of vbuf (once, before the layer loop)
__global__ __launch_bounds__(1024) void vpad_zero(unsigned* __restrict__ vb32)
{
    vb32[(size_t)NE * 64 + threadIdx.x] = 0u;
}

// ---------------- t|u = h @ ew1 halves — merged single pass over f32 h ----------------
// Reads h ONCE (was twice in the 2-dispatch form), packs once; both weight tiles in
// 67.6 KB LDS. t half folds eb1: t' = t + b1. Grid 392 -> exactly 1 group per wave.
__global__ __launch_bounds__(512) void tu_mfma(
    const float* __restrict__ h, const float* __restrict__ ew1_l,
    const float* __restrict__ eb1_l,
    short* __restrict__ tb, short* __restrict__ ub)
{
    __shared__ __align__(16) short BTt[128 * BTS];
    __shared__ __align__(16) short BTu[128 * BTS];
    for (int i = threadIdx.x; i < 128 * 128; i += 512) {
        int c = i >> 7, k = i & 127;
        BTt[c * BTS + k] = f2bf(ew1_l[k * HD + c]);
        BTu[c * BTS + k] = f2bf(ew1_l[(128 + k) * HD + c]);
    }
    int wv = threadIdx.x >> 6, lane = threadIdx.x & 63;
    int ln15 = lane & 15, quad = lane >> 4;
    __syncthreads();

    for (int g = blockIdx.x * 8 + wv; g < NG16; g += gridDim.x * 8) {
        int row = g * 16 + ln15;
        const float* hrow = h + row * HD;
        bf16x8 afr[4];
        #pragma unroll
        for (int kt = 0; kt < 4; ++kt) {
            float4 x0 = *(const float4*)(hrow + kt * 32 + quad * 8);
            float4 x1 = *(const float4*)(hrow + kt * 32 + quad * 8 + 4);
            afr[kt] = pack8(x0, x1);
        }
        #pragma unroll
        for (int ct = 0; ct < 8; ++ct) {
            f32x4 acc = {0.f, 0.f, 0.f, 0.f};
            #pragma unroll
            for (int kt = 0; kt < 4; ++kt) {
                bf16x8 bfr = *(const bf16x8*)&BTt[(ct * 16 + ln15) * BTS + kt * 32 + quad * 8];
                acc = __builtin_amdgcn_mfma_f32_16x16x32_bf16(afr[kt], bfr, acc, 0, 0, 0);
            }
            int col = ct * 16 + ln15;
            float bb = eb1_l[col];
            #pragma unroll
            for (int r4 = 0; r4 < 4; ++r4) {
                int orow = g * 16 + quad * 4 + r4;
                tb[orow * HD + col] = f2bf(acc[r4] + bb);
            }
        }
        #pragma unroll
        for (int ct = 0; ct < 8; ++ct) {
            f32x4 acc = {0.f, 0.f, 0.f, 0.f};
            #pragma unroll
            for (int kt = 0; kt < 4; ++kt) {
                bf16x8 bfr = *(const bf16x8*)&BTu[(ct * 16 + ln15) * BTS + kt * 32 + quad * 8];
                acc = __builtin_amdgcn_mfma_f32_16x16x32_bf16(afr[kt], bfr, acc, 0, 0, 0);
            }
            int col = ct * 16 + ln15;
            #pragma unroll
            for (int r4 = 0; r4 < 4; ++r4) {
                int orow = g * 16 + quad * 4 + r4;
                ub[orow * HD + col] = f2bf(acc[r4]);
            }
        }
    }
}

// ---------------- edge v-compute: streaming, no LDS, no MFMA ----------------
__global__ __launch_bounds__(512) void edge_v_kernel(
    const short* __restrict__ tb, const short* __restrict__ ub,
    const int4* __restrict__ ed_p, const int* __restrict__ eidx,
    const float* __restrict__ eattr,
    const float* __restrict__ ew1_l,
    short* __restrict__ vbuf)
{
    int cp = threadIdx.x & 63;
    int c0 = cp * 2;
    f32x2 wr2  = *(const f32x2*)&ew1_l[256 * HD + c0];
    f32x2 wa02 = *(const f32x2*)&ew1_l[257 * HD + c0];
    f32x2 wa12 = *(const f32x2*)&ew1_l[258 * HD + c0];
    f32x2 wa22 = *(const f32x2*)&ew1_l[259 * HD + c0];
    f32x2 wa32 = *(const f32x2*)&ew1_l[260 * HD + c0];

    const unsigned* tb32 = (const unsigned*)tb;
    const unsigned* ub32 = (const unsigned*)ub;
    const float4*   ea4  = (const float4*)eattr;
    unsigned*       vb32 = (unsigned*)vbuf;

    int w  = (blockIdx.x * 512 + threadIdx.x) >> 6;
    int nw = gridDim.x * 8;

    for (int p0 = w * 4; p0 < NE; p0 += nw * 4) {      // NE % 4 == 0
        int4 edv[4]; unsigned twv[4], uwv[4]; float4 eav[4];
        #pragma unroll
        for (int j = 0; j < 4; ++j) edv[j] = ed_p[p0 + j];
        #pragma unroll
        for (int j = 0; j < 4; ++j) {
            twv[j] = tb32[edv[j].x + cp];
            uwv[j] = ub32[edv[j].y + cp];
            eav[j] = ea4[eidx[p0 + j]];
        }
        #pragma unroll
        for (int j = 0; j < 4; ++j) {
            float rad = __int_as_float(edv[j].z);
            f32x2 s;
            s.x = __uint_as_float(twv[j] << 16)        + __uint_as_float(uwv[j] << 16);
            s.y = __uint_as_float(twv[j] & 0xFFFF0000u) + __uint_as_float(uwv[j] & 0xFFFF0000u);
            s += rad * wr2;
            s += eav[j].x * wa02;
            s += eav[j].y * wa12;
            s += eav[j].z * wa22;
            s += eav[j].w * wa32;
            vb32[(size_t)(p0 + j) * 64 + cp] = f2bf2u(silu_f(s.x), silu_f(s.y));
        }
    }
}

// ---------------- edge MFMA + aggregation: wave per node (round-3 body, proven 125 us) ----------------
// b2 hoisted to 8 registers. Unclamped bounds (clamps spill, r4/r5). Further SWP attempts
// (r1/r6/r7) all neutral-or-worse: compiler sinks prefetches / phi-joins force waits.
__global__ __launch_bounds__(512) void edge_agg_kernel(
    const short* __restrict__ vbuf, const int4* __restrict__ ed_p,
    const int* __restrict__ rowptr,
    const float* __restrict__ ew2_l, const float* __restrict__ eb2_l,
    short* __restrict__ aggb)
{
    __shared__ __align__(16) short BT[128 * BTS];

    for (int i = threadIdx.x; i < 128 * 128; i += 512) {
        int k = i >> 7, n = i & 127;
        BT[n * BTS + k] = f2bf(ew2_l[i]);
    }

    int lane = threadIdx.x & 63;
    int wv   = threadIdx.x >> 6;
    int ln15 = lane & 15;
    int quad = lane >> 4;

    float b2r[8];
    #pragma unroll
    for (int ct = 0; ct < 8; ++ct) b2r[ct] = eb2_l[ct * 16 + ln15];
    __syncthreads();

    for (int n = blockIdx.x * 8 + wv; n < NN; n += gridDim.x * 8) {
        int s = rowptr[n], en = rowptr[n + 1];

        float sums[8];
        #pragma unroll
        for (int ct = 0; ct < 8; ++ct) sums[ct] = 0.f;

        for (int base = s; base < en; base += 16) {
            const short* vrow = vbuf + (size_t)(base + ln15) * HD + quad * 8;
            bf16x8 afr[4];
            #pragma unroll
            for (int kt = 0; kt < 4; ++kt)
                afr[kt] = *(const bf16x8*)(vrow + kt * 32);

            int pr = base + quad * 4;
            float mk0 = (pr + 0 < en) ? __int_as_float(ed_p[pr + 0].w) : 0.f;
            float mk1 = (pr + 1 < en) ? __int_as_float(ed_p[pr + 1].w) : 0.f;
            float mk2 = (pr + 2 < en) ? __int_as_float(ed_p[pr + 2].w) : 0.f;
            float mk3 = (pr + 3 < en) ? __int_as_float(ed_p[pr + 3].w) : 0.f;

            #pragma unroll
            for (int ct = 0; ct < 8; ++ct) {
                f32x4 acc = {0.f, 0.f, 0.f, 0.f};
                #pragma unroll
                for (int kt = 0; kt < 4; ++kt) {
                    bf16x8 bfr = *(const bf16x8*)&BT[(ct * 16 + ln15) * BTS + kt * 32 + quad * 8];
                    acc = __builtin_amdgcn_mfma_f32_16x16x32_bf16(afr[kt], bfr, acc, 0, 0, 0);
                }
                float b2c = b2r[ct];
                sums[ct] += silu_f(acc[0] + b2c) * mk0 + silu_f(acc[1] + b2c) * mk1
                          + silu_f(acc[2] + b2c) * mk2 + silu_f(acc[3] + b2c) * mk3;
            }
        }

        #pragma unroll
        for (int ct = 0; ct < 8; ++ct) {
            float v = sums[ct];
            v += __shfl_xor(v, 16, 64);
            v += __shfl_xor(v, 32, 64);
            sums[ct] = v;
        }
        float vA = (quad & 2) ? ((quad & 1) ? sums[6] : sums[4])
                              : ((quad & 1) ? sums[2] : sums[0]);
        float vB = (quad & 2) ? ((quad & 1) ? sums[7] : sums[5])
                              : ((quad & 1) ? sums[3] : sums[1]);
        int colA = quad * 32 + ln15;
        aggb[(size_t)n * HD + colA]      = f2bf(vA);
        aggb[(size_t)n * HD + colA + 16] = f2bf(vB);
    }
}

// ---------------- node MLP layer 1 (f32 h + pack; agg bf16; h0 via precomputed h0b) ----------------
__global__ __launch_bounds__(512) void nk1_mfma(
    const float* __restrict__ h, const short* __restrict__ aggb,
    const short* __restrict__ h0b,
    const float* __restrict__ nw1_l, const float* __restrict__ nb1_l,
    short* __restrict__ qb)
{
    __shared__ __align__(16) short BT[64 * K1S];
    int c0 = blockIdx.y * 64;
    for (int i = threadIdx.x; i < 64 * 288; i += 512) {
        int c = i / 288, k = i - c * 288;
        BT[c * K1S + k] = (k < 267) ? f2bf(nw1_l[k * HD + c0 + c]) : (short)0;
    }
    int wv = threadIdx.x >> 6, lane = threadIdx.x & 63;
    int ln15 = lane & 15, quad = lane >> 4;
    __syncthreads();

    for (int g = blockIdx.x * 8 + wv; g < NG16; g += gridDim.x * 8) {
        int row = g * 16 + ln15;
        const float* hrow = h + row * HD;
        const short* arow = aggb + (size_t)row * HD + quad * 8;
        bf16x8 afr[9];
        #pragma unroll
        for (int kt = 0; kt < 4; ++kt) {
            float4 x0 = *(const float4*)(hrow + kt * 32 + quad * 8);
            float4 x1 = *(const float4*)(hrow + kt * 32 + quad * 8 + 4);
            afr[kt] = pack8(x0, x1);
        }
        #pragma unroll
        for (int kt = 0; kt < 4; ++kt)
            afr[4 + kt] = *(const bf16x8*)(arow + kt * 32);
        afr[8] = *(const bf16x8*)(h0b + (size_t)row * 32 + quad * 8);

        #pragma unroll
        for (int ct = 0; ct < 4; ++ct) {
            f32x4 acc = {0.f, 0.f, 0.f, 0.f};
            #pragma unroll
            for (int kt = 0; kt < 9; ++kt) {
                bf16x8 bfr = *(const bf16x8*)&BT[(ct * 16 + ln15) * K1S + kt * 32 + quad * 8];
                acc = __builtin_amdgcn_mfma_f32_16x16x32_bf16(afr[kt], bfr, acc, 0, 0, 0);
            }
            int col = c0 + ct * 16 + ln15;
            float b = nb1_l[col];
            #pragma unroll
            for (int r4 = 0; r4 < 4; ++r4) {
                int orow = g * 16 + quad * 4 + r4;
                qb[orow * HD + col] = f2bf(silu_f(acc[r4] + b));
            }
        }
    }
}

// ---------------- node MLP layer 2 + residual (persistent MFMA) ----------------
__global__ __launch_bounds__(512) void nk2_mfma(
    const short* __restrict__ qb, const float* __restrict__ nw2_l,
    const float* __restrict__ nb2_l, float* __restrict__ h)
{
    __shared__ __align__(16) short BT[128 * BTS];
    for (int i = threadIdx.x; i < 128 * 128; i += 512) {
        int c = i >> 7, k = i & 127;
        BT[c * BTS + k] = f2bf(nw2_l[k * HD + c]);
    }
    int wv = threadIdx.x >> 6, lane = threadIdx.x & 63;
    int ln15 = lane & 15, quad = lane >> 4;
    __syncthreads();

    for (int g = blockIdx.x * 8 + wv; g < NG16; g += gridDim.x * 8) {
        int row = g * 16 + ln15;
        bf16x8 afr[4];
        #pragma unroll
        for (int kt = 0; kt < 4; ++kt)
            afr[kt] = *(const bf16x8*)(qb + row * HD + kt * 32 + quad * 8);

        #pragma unroll
        for (int ct = 0; ct < 8; ++ct) {
            f32x4 acc = {0.f, 0.f, 0.f, 0.f};
            #pragma unroll
            for (int kt = 0; kt < 4; ++kt) {
                bf16x8 bfr = *(const bf16x8*)&BT[(ct * 16 + ln15) * BTS + kt * 32 + quad * 8];
                acc = __builtin_amdgcn_mfma_f32_16x16x32_bf16(afr[kt], bfr, acc, 0, 0, 0);
            }
            int col = ct * 16 + ln15;
            float b = nb2_l[col];
            #pragma unroll
            for (int r4 = 0; r4 < 4; ++r4) {
                int orow = g * 16 + quad * 4 + r4;
                h[orow * HD + col] += acc[r4] + b;
            }
        }
    }
}

extern "C" void kernel_launch(void* const* d_in, const int* in_sizes, int n_in,
                              void* d_out, int out_size, void* d_ws, size_t ws_size,
                              hipStream_t stream)
{
    const float* h0    = (const float*)d_in[0];
    const float* x     = (const float*)d_in[1];
    const int*   ei    = (const int*)d_in[2];
    const float* eattr = (const float*)d_in[3];
    const float* emask = (const float*)d_in[5];
    const float* emb_w = (const float*)d_in[7];
    const float* emb_b = (const float*)d_in[8];
    const float* ew1   = (const float*)d_in[9];
    const float* eb1   = (const float*)d_in[10];
    const float* ew2   = (const float*)d_in[11];
    const float* eb2   = (const float*)d_in[12];
    const float* nw1   = (const float*)d_in[13];
    const float* nb1   = (const float*)d_in[14];
    const float* nw2   = (const float*)d_in[15];
    const float* nb2   = (const float*)d_in[16];

    float* h = (float*)d_out;

    // workspace layout (~263 MB of 268.4 MB)
    short*  tb     = (short*)d_ws;                          // NN*HD bf16
    short*  ub     = tb + (size_t)NN * HD;                  // NN*HD bf16
    short*  aggb   = ub + (size_t)NN * HD;                  // NN*HD bf16
    short*  vbuf   = aggb + (size_t)NN * HD;                // (NE+16)*HD bf16
    int4*   ed_p   = (int4*)(vbuf + (size_t)(NE + 16) * HD);// NE int4
    int*    rowptr = (int*)(ed_p + NE);                     // NN+1
    int*    cnt    = rowptr + NN + 1;                       // NN
    int*    cursor = cnt + NN;                              // NN
    int*    eidx   = cursor + NN;                           // NE
    int*    bsum   = eidx + NE;                             // NB
    int*    boff   = bsum + NB;                             // NB
    short*  h0b    = (short*)(boff + NB);                   // NN*32 bf16 (3.2 MB)
    short*  qb     = tb;                                    // alias (tb dead by nk1)

    csr_zero<<<(NN + 255) / 256, 256, 0, stream>>>(cnt);
    csr_hist<<<NE / 256, 256, 0, stream>>>(ei, cnt);
    csr_blocksum<<<NB, 256, 0, stream>>>(cnt, bsum);
    csr_scanpart<<<1, 256, 0, stream>>>(bsum, boff, rowptr);
    csr_emit<<<NB, 256, 0, stream>>>(cnt, boff, rowptr, cursor);
    csr_fill<<<NE / 256, 256, 0, stream>>>(ei, cursor, eidx);
    edge_pre<<<NE / 256, 256, 0, stream>>>(ei, eidx, x, emask, ed_p);
    vpad_zero<<<1, 1024, 0, stream>>>((unsigned*)vbuf);
    h0_pack<<<(NN * 32 + 255) / 256, 256, 0, stream>>>(h0, h0b);

    embed_kernel<<<(NN * HD + 255) / 256, 256, 0, stream>>>(h0, emb_w, emb_b, h);

    dim3 gn1(128, 2);
    for (int l = 0; l < NL; ++l) {
        tu_mfma<<<392, 512, 0, stream>>>(h, ew1 + l * 261 * HD, eb1 + l * HD, tb, ub);
        edge_v_kernel<<<1024, 512, 0, stream>>>(tb, ub, ed_p, eidx, eattr,
            ew1 + l * 261 * HD, vbuf);
        edge_agg_kernel<<<1024, 512, 0, stream>>>(vbuf, ed_p, rowptr,
            ew2 + l * HD * HD, eb2 + l * HD, aggb);
        nk1_mfma<<<gn1, 512, 0, stream>>>(h, aggb, h0b,
            nw1 + l * 267 * HD, nb1 + l * HD, qb);
        nk2_mfma<<<128, 512, 0, stream>>>(qb, nw2 + l * HD * HD, nb2 + l * HD, h);
    }
}

// Round 10
// 1384.776 us; speedup vs baseline: 1.1218x; 1.1126x over previous
//
#include <hip/hip_runtime.h>

#define NN 50000
#define NE 800000
#define HD 128
#define INN 11
#define NL 4
#define NG16 3125        // 16-row node groups
#define BTS 132          // LDS K stride (shorts)
#define K1S 292          // nk1 K stride
#define NB  196          // CSR scan blocks (196*256 >= NN)

typedef __attribute__((ext_vector_type(8))) short bf16x8;
typedef __attribute__((ext_vector_type(4))) float f32x4;
typedef __attribute__((ext_vector_type(2))) float f32x2;

__device__ __forceinline__ float silu_f(float x) {
    return x * __builtin_amdgcn_rcpf(1.0f + __expf(-x));
}

__device__ __forceinline__ short f2bf(float x) {
    unsigned u = __float_as_uint(x);
    return (short)((u + 0x7FFFu + ((u >> 16) & 1u)) >> 16);
}
__device__ __forceinline__ unsigned f2bf2u(float lo, float hi) {
    unsigned a = __float_as_uint(lo), b = __float_as_uint(hi);
    a = (a + 0x7FFFu + ((a >> 16) & 1u)) >> 16;
    b = (b + 0x7FFFu + ((b >> 16) & 1u)) & 0xFFFF0000u;
    return a | b;
}
__device__ __forceinline__ bf16x8 pack8(float4 a, float4 b) {
    bf16x8 r;
    r[0] = f2bf(a.x); r[1] = f2bf(a.y); r[2] = f2bf(a.z); r[3] = f2bf(a.w);
    r[4] = f2bf(b.x); r[5] = f2bf(b.y); r[6] = f2bf(b.z); r[7] = f2bf(b.w);
    return r;
}

// ---------------- embedding ----------------
__global__ __launch_bounds__(256) void embed_kernel(
    const float* __restrict__ h0, const float* __restrict__ w,
    const float* __restrict__ b, float* __restrict__ h)
{
    int idx = blockIdx.x * 256 + threadIdx.x;
    if (idx >= NN * HD) return;
    int n = idx >> 7, j = idx & 127;
    float acc = b[j];
    #pragma unroll
    for (int k = 0; k < INN; ++k)
        acc += h0[n * INN + k] * w[k * HD + j];
    h[idx] = acc;
}

// ---------------- h0 bf16 pack (once): layout matches afr[8] fragment ----------------
__global__ __launch_bounds__(256) void h0_pack(
    const float* __restrict__ h0, short* __restrict__ h0b)
{
    int idx = blockIdx.x * 256 + threadIdx.x;
    if (idx >= NN * 32) return;
    int n = idx >> 5, j = idx & 31;
    h0b[idx] = (j < INN) ? f2bf(h0[n * INN + j]) : (short)0;
}

// ---------------- CSR build ----------------
__global__ __launch_bounds__(256) void csr_zero(int* __restrict__ cnt)
{
    int i = blockIdx.x * 256 + threadIdx.x;
    if (i < NN) cnt[i] = 0;
}

__global__ __launch_bounds__(256) void csr_hist(const int* __restrict__ ei, int* __restrict__ cnt)
{
    int e = blockIdx.x * 256 + threadIdx.x;
    atomicAdd(&cnt[ei[e]], 1);
}

__global__ __launch_bounds__(256) void csr_blocksum(
    const int* __restrict__ cnt, int* __restrict__ bsum)
{
    __shared__ int red[4];
    int j = blockIdx.x * 256 + threadIdx.x;
    int v = (j < NN) ? cnt[j] : 0;
    #pragma unroll
    for (int off = 1; off < 64; off <<= 1) v += __shfl_xor(v, off, 64);
    int lane = threadIdx.x & 63, wv = threadIdx.x >> 6;
    if (lane == 0) red[wv] = v;
    __syncthreads();
    if (threadIdx.x == 0)
        bsum[blockIdx.x] = red[0] + red[1] + red[2] + red[3];
}

__global__ __launch_bounds__(256) void csr_scanpart(
    const int* __restrict__ bsum, int* __restrict__ boff, int* __restrict__ rowptr)
{
    __shared__ int part[256];
    int t = threadIdx.x;
    int v = (t < NB) ? bsum[t] : 0;
    part[t] = v;
    __syncthreads();
    #pragma unroll
    for (int off = 1; off < 256; off <<= 1) {
        int tmp = (t >= off) ? part[t - off] : 0;
        __syncthreads();
        part[t] += tmp;
        __syncthreads();
    }
    if (t < NB) boff[t] = part[t] - v;          // exclusive
    if (t == NB - 1) rowptr[NN] = part[t];      // total
}

__global__ __launch_bounds__(256) void csr_emit(
    const int* __restrict__ cnt, const int* __restrict__ boff,
    int* __restrict__ rowptr, int* __restrict__ cursor)
{
    __shared__ int part[256];
    int t = threadIdx.x;
    int j = blockIdx.x * 256 + t;
    int v = (j < NN) ? cnt[j] : 0;
    part[t] = v;
    __syncthreads();
    #pragma unroll
    for (int off = 1; off < 256; off <<= 1) {
        int tmp = (t >= off) ? part[t - off] : 0;
        __syncthreads();
        part[t] += tmp;
        __syncthreads();
    }
    if (j < NN) {
        int r = boff[blockIdx.x] + part[t] - v;
        rowptr[j] = r;
        cursor[j] = r;
    }
}

// ---------------- CSR fill + per-edge data in one pass (eidx eliminated) ----------------
// ed = {r*64, c*64, rad, mask}; ea_p = bf16x4 edge_attr, BOTH in CSR order.
__global__ __launch_bounds__(256) void csr_fill_pre(
    const int* __restrict__ ei, int* __restrict__ cursor,
    const float* __restrict__ x, const float* __restrict__ emask,
    const float* __restrict__ eattr,
    int4* __restrict__ ed_p, ushort4* __restrict__ ea_p)
{
    int e = blockIdx.x * 256 + threadIdx.x;
    int r = ei[e], c = ei[NE + e];
    int p = atomicAdd(&cursor[r], 1);
    float dx = x[3 * r]     - x[3 * c];
    float dy = x[3 * r + 1] - x[3 * c + 1];
    float dz = x[3 * r + 2] - x[3 * c + 2];
    float rad = dx * dx + dy * dy + dz * dz;
    ed_p[p] = make_int4(r * 64, c * 64, __float_as_int(rad), __float_as_int(emask[e]));
    float4 ea = ((const float4*)eattr)[e];
    ushort4 eb;
    eb.x = (unsigned short)f2bf(ea.x);
    eb.y = (unsigned short)f2bf(ea.y);
    eb.z = (unsigned short)f2bf(ea.z);
    eb.w = (unsigned short)f2bf(ea.w);
    ea_p[p] = eb;
}

// zero the 16 slack rows of vbuf (once, before the layer loop)
__global__ __launch_bounds__(1024) void vpad_zero(unsigned* __restrict__ vb32)
{
    vb32[(size_t)NE * 64 + threadIdx.x] = 0u;
}

// ---------------- t|u = h @ ew1 halves (split dim3(x,2), 34 KB LDS — proven form) ----------------
// y==0 (t half) folds the eb1 bias into the output: t' = t + b1.
// (r8/r9 merged 68KB-LDS variant regressed ~22 us/layer: 2 blocks/CU + grid imbalance.)
__global__ __launch_bounds__(512) void tu_mfma(
    const float* __restrict__ h, const float* __restrict__ ew1_l,
    const float* __restrict__ eb1_l,
    short* __restrict__ tb, short* __restrict__ ub)
{
    __shared__ __align__(16) short BT[128 * BTS];
    const float* wsrc = ew1_l + (blockIdx.y ? 128 * HD : 0);
    short* outp = blockIdx.y ? ub : tb;
    for (int i = threadIdx.x; i < 128 * 128; i += 512) {
        int c = i >> 7, k = i & 127;
        BT[c * BTS + k] = f2bf(wsrc[k * HD + c]);
    }
    int wv = threadIdx.x >> 6, lane = threadIdx.x & 63;
    int ln15 = lane & 15, quad = lane >> 4;
    __syncthreads();

    for (int g = blockIdx.x * 8 + wv; g < NG16; g += gridDim.x * 8) {
        int row = g * 16 + ln15;
        const float* hrow = h + row * HD;
        bf16x8 afr[4];
        #pragma unroll
        for (int kt = 0; kt < 4; ++kt) {
            float4 x0 = *(const float4*)(hrow + kt * 32 + quad * 8);
            float4 x1 = *(const float4*)(hrow + kt * 32 + quad * 8 + 4);
            afr[kt] = pack8(x0, x1);
        }
        #pragma unroll
        for (int ct = 0; ct < 8; ++ct) {
            f32x4 acc = {0.f, 0.f, 0.f, 0.f};
            #pragma unroll
            for (int kt = 0; kt < 4; ++kt) {
                bf16x8 bfr = *(const bf16x8*)&BT[(ct * 16 + ln15) * BTS + kt * 32 + quad * 8];
                acc = __builtin_amdgcn_mfma_f32_16x16x32_bf16(afr[kt], bfr, acc, 0, 0, 0);
            }
            int col = ct * 16 + ln15;
            float bb = blockIdx.y ? 0.f : eb1_l[col];
            #pragma unroll
            for (int r4 = 0; r4 < 4; ++r4) {
                int orow = g * 16 + quad * 4 + r4;
                outp[orow * HD + col] = f2bf(acc[r4] + bb);
            }
        }
    }
}

// ---------------- edge v-compute: streaming, no LDS, no MFMA ----------------
// All loads now sequential (ed_p, ea_p CSR-ordered) except the two row gathers:
// t-row (L1-hot: CSR-consecutive edges share the row) and u-row (irreducible).
__global__ __launch_bounds__(512) void edge_v_kernel(
    const short* __restrict__ tb, const short* __restrict__ ub,
    const int4* __restrict__ ed_p, const ushort4* __restrict__ ea_p,
    const float* __restrict__ ew1_l,
    short* __restrict__ vbuf)
{
    int cp = threadIdx.x & 63;
    int c0 = cp * 2;
    f32x2 wr2  = *(const f32x2*)&ew1_l[256 * HD + c0];
    f32x2 wa02 = *(const f32x2*)&ew1_l[257 * HD + c0];
    f32x2 wa12 = *(const f32x2*)&ew1_l[258 * HD + c0];
    f32x2 wa22 = *(const f32x2*)&ew1_l[259 * HD + c0];
    f32x2 wa32 = *(const f32x2*)&ew1_l[260 * HD + c0];

    const unsigned* tb32 = (const unsigned*)tb;
    const unsigned* ub32 = (const unsigned*)ub;
    unsigned*       vb32 = (unsigned*)vbuf;

    int w  = (blockIdx.x * 512 + threadIdx.x) >> 6;
    int nw = gridDim.x * 8;

    for (int p0 = w * 4; p0 < NE; p0 += nw * 4) {      // NE % 4 == 0
        int4 edv[4]; unsigned twv[4], uwv[4]; ushort4 eav[4];
        #pragma unroll
        for (int j = 0; j < 4; ++j) edv[j] = ed_p[p0 + j];
        #pragma unroll
        for (int j = 0; j < 4; ++j) {
            twv[j] = tb32[edv[j].x + cp];
            uwv[j] = ub32[edv[j].y + cp];
            eav[j] = ea_p[p0 + j];
        }
        #pragma unroll
        for (int j = 0; j < 4; ++j) {
            float rad = __int_as_float(edv[j].z);
            float e0 = __uint_as_float((unsigned)eav[j].x << 16);
            float e1 = __uint_as_float((unsigned)eav[j].y << 16);
            float e2 = __uint_as_float((unsigned)eav[j].z << 16);
            float e3 = __uint_as_float((unsigned)eav[j].w << 16);
            f32x2 s;
            s.x = __uint_as_float(twv[j] << 16)        + __uint_as_float(uwv[j] << 16);
            s.y = __uint_as_float(twv[j] & 0xFFFF0000u) + __uint_as_float(uwv[j] & 0xFFFF0000u);
            s += rad * wr2;
            s += e0 * wa02;
            s += e1 * wa12;
            s += e2 * wa22;
            s += e3 * wa32;
            vb32[(size_t)(p0 + j) * 64 + cp] = f2bf2u(silu_f(s.x), silu_f(s.y));
        }
    }
}

// ---------------- edge MFMA + aggregation: wave per node (round-3 body, proven floor) ----------------
// b2 hoisted to 8 registers. Unclamped bounds (clamps spill, r4/r5). Further SWP attempts
// (r1/r6/r7) all neutral-or-worse: compiler sinks prefetches / phi-joins force waits.
__global__ __launch_bounds__(512) void edge_agg_kernel(
    const short* __restrict__ vbuf, const int4* __restrict__ ed_p,
    const int* __restrict__ rowptr,
    const float* __restrict__ ew2_l, const float* __restrict__ eb2_l,
    short* __restrict__ aggb)
{
    __shared__ __align__(16) short BT[128 * BTS];

    for (int i = threadIdx.x; i < 128 * 128; i += 512) {
        int k = i >> 7, n = i & 127;
        BT[n * BTS + k] = f2bf(ew2_l[i]);
    }

    int lane = threadIdx.x & 63;
    int wv   = threadIdx.x >> 6;
    int ln15 = lane & 15;
    int quad = lane >> 4;

    float b2r[8];
    #pragma unroll
    for (int ct = 0; ct < 8; ++ct) b2r[ct] = eb2_l[ct * 16 + ln15];
    __syncthreads();

    for (int n = blockIdx.x * 8 + wv; n < NN; n += gridDim.x * 8) {
        int s = rowptr[n], en = rowptr[n + 1];

        float sums[8];
        #pragma unroll
        for (int ct = 0; ct < 8; ++ct) sums[ct] = 0.f;

        for (int base = s; base < en; base += 16) {
            const short* vrow = vbuf + (size_t)(base + ln15) * HD + quad * 8;
            bf16x8 afr[4];
            #pragma unroll
            for (int kt = 0; kt < 4; ++kt)
                afr[kt] = *(const bf16x8*)(vrow + kt * 32);

            int pr = base + quad * 4;
            float mk0 = (pr + 0 < en) ? __int_as_float(ed_p[pr + 0].w) : 0.f;
            float mk1 = (pr + 1 < en) ? __int_as_float(ed_p[pr + 1].w) : 0.f;
            float mk2 = (pr + 2 < en) ? __int_as_float(ed_p[pr + 2].w) : 0.f;
            float mk3 = (pr + 3 < en) ? __int_as_float(ed_p[pr + 3].w) : 0.f;

            #pragma unroll
            for (int ct = 0; ct < 8; ++ct) {
                f32x4 acc = {0.f, 0.f, 0.f, 0.f};
                #pragma unroll
                for (int kt = 0; kt < 4; ++kt) {
                    bf16x8 bfr = *(const bf16x8*)&BT[(ct * 16 + ln15) * BTS + kt * 32 + quad * 8];
                    acc = __builtin_amdgcn_mfma_f32_16x16x32_bf16(afr[kt], bfr, acc, 0, 0, 0);
                }
                float b2c = b2r[ct];
                sums[ct] += silu_f(acc[0] + b2c) * mk0 + silu_f(acc[1] + b2c) * mk1
                          + silu_f(acc[2] + b2c) * mk2 + silu_f(acc[3] + b2c) * mk3;
            }
        }

        #pragma unroll
        for (int ct = 0; ct < 8; ++ct) {
            float v = sums[ct];
            v += __shfl_xor(v, 16, 64);
            v += __shfl_xor(v, 32, 64);
            sums[ct] = v;
        }
        float vA = (quad & 2) ? ((quad & 1) ? sums[6] : sums[4])
                              : ((quad & 1) ? sums[2] : sums[0]);
        float vB = (quad & 2) ? ((quad & 1) ? sums[7] : sums[5])
                              : ((quad & 1) ? sums[3] : sums[1]);
        int colA = quad * 32 + ln15;
        aggb[(size_t)n * HD + colA]      = f2bf(vA);
        aggb[(size_t)n * HD + colA + 16] = f2bf(vB);
    }
}

// ---------------- node MLP layer 1 (f32 h + pack; agg bf16; h0 via precomputed h0b) ----------------
__global__ __launch_bounds__(512) void nk1_mfma(
    const float* __restrict__ h, const short* __restrict__ aggb,
    const short* __restrict__ h0b,
    const float* __restrict__ nw1_l, const float* __restrict__ nb1_l,
    short* __restrict__ qb)
{
    __shared__ __align__(16) short BT[64 * K1S];
    int c0 = blockIdx.y * 64;
    for (int i = threadIdx.x; i < 64 * 288; i += 512) {
        int c = i / 288, k = i - c * 288;
        BT[c * K1S + k] = (k < 267) ? f2bf(nw1_l[k * HD + c0 + c]) : (short)0;
    }
    int wv = threadIdx.x >> 6, lane = threadIdx.x & 63;
    int ln15 = lane & 15, quad = lane >> 4;
    __syncthreads();

    for (int g = blockIdx.x * 8 + wv; g < NG16; g += gridDim.x * 8) {
        int row = g * 16 + ln15;
        const float* hrow = h + row * HD;
        const short* arow = aggb + (size_t)row * HD + quad * 8;
        bf16x8 afr[9];
        #pragma unroll
        for (int kt = 0; kt < 4; ++kt) {
            float4 x0 = *(const float4*)(hrow + kt * 32 + quad * 8);
            float4 x1 = *(const float4*)(hrow + kt * 32 + quad * 8 + 4);
            afr[kt] = pack8(x0, x1);
        }
        #pragma unroll
        for (int kt = 0; kt < 4; ++kt)
            afr[4 + kt] = *(const bf16x8*)(arow + kt * 32);
        afr[8] = *(const bf16x8*)(h0b + (size_t)row * 32 + quad * 8);

        #pragma unroll
        for (int ct = 0; ct < 4; ++ct) {
            f32x4 acc = {0.f, 0.f, 0.f, 0.f};
            #pragma unroll
            for (int kt = 0; kt < 9; ++kt) {
                bf16x8 bfr = *(const bf16x8*)&BT[(ct * 16 + ln15) * K1S + kt * 32 + quad * 8];
                acc = __builtin_amdgcn_mfma_f32_16x16x32_bf16(afr[kt], bfr, acc, 0, 0, 0);
            }
            int col = c0 + ct * 16 + ln15;
            float b = nb1_l[col];
            #pragma unroll
            for (int r4 = 0; r4 < 4; ++r4) {
                int orow = g * 16 + quad * 4 + r4;
                qb[orow * HD + col] = f2bf(silu_f(acc[r4] + b));
            }
        }
    }
}

// ---------------- node MLP layer 2 + residual (persistent MFMA) ----------------
__global__ __launch_bounds__(512) void nk2_mfma(
    const short* __restrict__ qb, const float* __restrict__ nw2_l,
    const float* __restrict__ nb2_l, float* __restrict__ h)
{
    __shared__ __align__(16) short BT[128 * BTS];
    for (int i = threadIdx.x; i < 128 * 128; i += 512) {
        int c = i >> 7, k = i & 127;
        BT[c * BTS + k] = f2bf(nw2_l[k * HD + c]);
    }
    int wv = threadIdx.x >> 6, lane = threadIdx.x & 63;
    int ln15 = lane & 15, quad = lane >> 4;
    __syncthreads();

    for (int g = blockIdx.x * 8 + wv; g < NG16; g += gridDim.x * 8) {
        int row = g * 16 + ln15;
        bf16x8 afr[4];
        #pragma unroll
        for (int kt = 0; kt < 4; ++kt)
            afr[kt] = *(const bf16x8*)(qb + row * HD + kt * 32 + quad * 8);

        #pragma unroll
        for (int ct = 0; ct < 8; ++ct) {
            f32x4 acc = {0.f, 0.f, 0.f, 0.f};
            #pragma unroll
            for (int kt = 0; kt < 4; ++kt) {
                bf16x8 bfr = *(const bf16x8*)&BT[(ct * 16 + ln15) * BTS + kt * 32 + quad * 8];
                acc = __builtin_amdgcn_mfma_f32_16x16x32_bf16(afr[kt], bfr, acc, 0, 0, 0);
            }
            int col = ct * 16 + ln15;
            float b = nb2_l[col];
            #pragma unroll
            for (int r4 = 0; r4 < 4; ++r4) {
                int orow = g * 16 + quad * 4 + r4;
                h[orow * HD + col] += acc[r4] + b;
            }
        }
    }
}

extern "C" void kernel_launch(void* const* d_in, const int* in_sizes, int n_in,
                              void* d_out, int out_size, void* d_ws, size_t ws_size,
                              hipStream_t stream)
{
    const float* h0    = (const float*)d_in[0];
    const float* x     = (const float*)d_in[1];
    const int*   ei    = (const int*)d_in[2];
    const float* eattr = (const float*)d_in[3];
    const float* emask = (const float*)d_in[5];
    const float* emb_w = (const float*)d_in[7];
    const float* emb_b = (const float*)d_in[8];
    const float* ew1   = (const float*)d_in[9];
    const float* eb1   = (const float*)d_in[10];
    const float* ew2   = (const float*)d_in[11];
    const float* eb2   = (const float*)d_in[12];
    const float* nw1   = (const float*)d_in[13];
    const float* nb1   = (const float*)d_in[14];
    const float* nw2   = (const float*)d_in[15];
    const float* nb2   = (const float*)d_in[16];

    float* h = (float*)d_out;

    // workspace layout (~266.2 MB of 268.4 MB; eidx eliminated, ea_p bf16)
    short*   tb     = (short*)d_ws;                          // NN*HD bf16
    short*   ub     = tb + (size_t)NN * HD;                  // NN*HD bf16
    short*   aggb   = ub + (size_t)NN * HD;                  // NN*HD bf16
    short*   vbuf   = aggb + (size_t)NN * HD;                // (NE+16)*HD bf16
    int4*    ed_p   = (int4*)(vbuf + (size_t)(NE + 16) * HD);// NE int4
    ushort4* ea_p   = (ushort4*)(ed_p + NE);                 // NE bf16x4 (8 B)
    int*     rowptr = (int*)(ea_p + NE);                     // NN+1
    int*     cnt    = rowptr + NN + 1;                       // NN
    int*     cursor = cnt + NN;                              // NN
    int*     bsum   = cursor + NN;                           // NB
    int*     boff   = bsum + NB;                             // NB
    short*   h0b    = (short*)(boff + NB);                   // NN*32 bf16 (3.2 MB)
    short*   qb     = tb;                                    // alias (tb dead by nk1)

    csr_zero<<<(NN + 255) / 256, 256, 0, stream>>>(cnt);
    csr_hist<<<NE / 256, 256, 0, stream>>>(ei, cnt);
    csr_blocksum<<<NB, 256, 0, stream>>>(cnt, bsum);
    csr_scanpart<<<1, 256, 0, stream>>>(bsum, boff, rowptr);
    csr_emit<<<NB, 256, 0, stream>>>(cnt, boff, rowptr, cursor);
    csr_fill_pre<<<NE / 256, 256, 0, stream>>>(ei, cursor, x, emask, eattr, ed_p, ea_p);
    vpad_zero<<<1, 1024, 0, stream>>>((unsigned*)vbuf);
    h0_pack<<<(NN * 32 + 255) / 256, 256, 0, stream>>>(h0, h0b);

    embed_kernel<<<(NN * HD + 255) / 256, 256, 0, stream>>>(h0, emb_w, emb_b, h);

    dim3 gtu(128, 2);
    dim3 gn1(128, 2);
    for (int l = 0; l < NL; ++l) {
        tu_mfma<<<gtu, 512, 0, stream>>>(h, ew1 + l * 261 * HD, eb1 + l * HD, tb, ub);
        edge_v_kernel<<<1024, 512, 0, stream>>>(tb, ub, ed_p, ea_p,
            ew1 + l * 261 * HD, vbuf);
        edge_agg_kernel<<<1024, 512, 0, stream>>>(vbuf, ed_p, rowptr,
            ew2 + l * HD * HD, eb2 + l * HD, aggb);
        nk1_mfma<<<gn1, 512, 0, stream>>>(h, aggb, h0b,
            nw1 + l * 267 * HD, nb1 + l * HD, qb);
        nk2_mfma<<<128, 512, 0, stream>>>(qb, nw2 + l * HD * HD, nb2 + l * HD, h);
    }
}